// Round 18
// baseline (264.773 us; speedup 1.0000x reference)
//
#include <hip/hip_runtime.h>
#include <math.h>

#define D_INNER 1024
#define STATE   16
#define DT_RANK 64
#define NPROJ   96
#define LSEQ    1024
#define NBATCH  2

#define LOG2E   1.4426950408889634f
#define NEG7L2  (-7.0f * LOG2E)     // clamp lo in log2 domain
#define P20L2   (20.0f * LOG2E)     // clamp hi in log2 domain

// ---- 64-lane inclusive scan via DPP (GCN idiom), 6 adds ----
template<int CTRL, int RMASK>
__device__ __forceinline__ float dppadd(float v) {
    int t = __builtin_amdgcn_update_dpp(0, __float_as_int(v), CTRL, RMASK, 0xf, false);
    return v + __int_as_float(t);
}
__device__ __forceinline__ float wave_iscan(float v) {
    v = dppadd<0x111, 0xf>(v);   // row_shr:1
    v = dppadd<0x112, 0xf>(v);   // row_shr:2
    v = dppadd<0x114, 0xf>(v);   // row_shr:4
    v = dppadd<0x118, 0xf>(v);   // row_shr:8
    v = dppadd<0x142, 0xa>(v);   // row_bcast:15 -> rows 1,3
    v = dppadd<0x143, 0xc>(v);   // row_bcast:31 -> rows 2,3
    return v;
}

// ============ Kernel 1: proj = x @ W_xproj ============
__global__ __launch_bounds__(768) void proj_kernel(
        const float* __restrict__ x, const float* __restrict__ Wx,
        float* __restrict__ projdt, float* __restrict__ Bg, float* __restrict__ Cg) {
    const int tid = threadIdx.x;
    const int j  = tid % 96;
    const int kq = tid / 96;              // 0..7
    const int row0 = blockIdx.x * 8;

    __shared__ float xs[8 * 1024];        // [r][k], 32 KB
    __shared__ float red[8][8][96];       // [kq][r][j], 24 KB

    {   // stage 8 rows of x (contiguous 32KB), coalesced float4
        const float4* src = (const float4*)(x + (size_t)row0 * 1024);
        #pragma unroll
        for (int i = 0; i < 3; ++i) {
            int idx = tid + 768 * i;      // 0..2047 float4s
            if (idx < 2048) {
                float4 v = src[idx];
                *(float4*)&xs[idx * 4] = v;
            }
        }
    }
    __syncthreads();

    const float* wp = Wx + (size_t)(kq * 128) * 96 + j;
    const float* xk = &xs[kq * 128];

    float a[8];
    #pragma unroll
    for (int r = 0; r < 8; ++r) a[r] = 0.f;

    #pragma unroll 8
    for (int k = 0; k < 128; ++k) {
        float w = wp[(size_t)k * 96];
        #pragma unroll
        for (int r = 0; r < 8; ++r)
            a[r] = fmaf(xk[r * 1024 + k], w, a[r]);
    }

    #pragma unroll
    for (int r = 0; r < 8; ++r) red[kq][r][j] = a[r];
    __syncthreads();

    {   // 768 outputs, one per thread
        const int r  = tid / 96;
        const int jj = tid % 96;
        float s = 0.f;
        #pragma unroll
        for (int p = 0; p < 8; ++p) s += red[p][r][jj];
        const int row = row0 + r;
        const int b = row >> 10, l = row & 1023;
        if (jj < 64)      projdt[(size_t)row * 64 + jj] = s;
        else if (jj < 80) Bg[((size_t)b * 16 + (jj - 64)) * 1024 + l] = s;
        else              Cg[((size_t)b * 16 + (jj - 80)) * 1024 + l] = s;
    }
}

// ============ Kernel 2: delta (transposed) + u_t = delta * x (transposed) ====
__global__ __launch_bounds__(256) void delta_kernel(
        const float* __restrict__ projdt, const float* __restrict__ Wdt,
        const float* __restrict__ bdt, const float* __restrict__ x,
        float* __restrict__ delta_t, float* __restrict__ u_t) {
    const int bid = blockIdx.x;
    const int lt = bid >> 4;
    const int dt = bid & 15;
    const int row0 = lt * 64;
    const int d0 = dt * 64;
    const int tid = threadIdx.x;

    __shared__ float pl[64][69];
    __shared__ float wlbuf[64 * 68];      // Wdt tile; reused for x tile later
    __shared__ float dtile[64][65];
    float (*wl)[68] = (float(*)[68])wlbuf;

    {
        const float4* src = (const float4*)(projdt + (size_t)row0 * 64);
        #pragma unroll
        for (int i = 0; i < 4; ++i) {
            int f4i = tid + 256 * i;
            float4 v = src[f4i];
            int l = f4i >> 4, k4 = (f4i & 15) << 2;
            pl[l][k4+0] = v.x; pl[l][k4+1] = v.y; pl[l][k4+2] = v.z; pl[l][k4+3] = v.w;
        }
    }
    {
        #pragma unroll
        for (int i = 0; i < 4; ++i) {
            int f4i = tid + 256 * i;
            int k = f4i >> 4, m4 = (f4i & 15) << 2;
            float4 v = *(const float4*)(Wdt + (size_t)k * 1024 + d0 + m4);
            *(float4*)&wl[k][m4] = v;
        }
    }
    __syncthreads();

    const int lsub = tid & 63;
    const int dq = tid >> 6;
    float acc[16];
    #pragma unroll
    for (int i = 0; i < 16; ++i) acc[i] = 0.f;

    #pragma unroll 4
    for (int k = 0; k < 64; ++k) {
        float p = pl[lsub][k];
        const float4* wr = (const float4*)&wl[k][dq * 16];
        float4 w0 = wr[0], w1 = wr[1], w2 = wr[2], w3 = wr[3];
        acc[0]  = fmaf(p, w0.x, acc[0]);  acc[1]  = fmaf(p, w0.y, acc[1]);
        acc[2]  = fmaf(p, w0.z, acc[2]);  acc[3]  = fmaf(p, w0.w, acc[3]);
        acc[4]  = fmaf(p, w1.x, acc[4]);  acc[5]  = fmaf(p, w1.y, acc[5]);
        acc[6]  = fmaf(p, w1.z, acc[6]);  acc[7]  = fmaf(p, w1.w, acc[7]);
        acc[8]  = fmaf(p, w2.x, acc[8]);  acc[9]  = fmaf(p, w2.y, acc[9]);
        acc[10] = fmaf(p, w2.z, acc[10]); acc[11] = fmaf(p, w2.w, acc[11]);
        acc[12] = fmaf(p, w3.x, acc[12]); acc[13] = fmaf(p, w3.y, acc[13]);
        acc[14] = fmaf(p, w3.z, acc[14]); acc[15] = fmaf(p, w3.w, acc[15]);
    }

    #pragma unroll
    for (int i = 0; i < 16; ++i) {
        float v = acc[i] + bdt[d0 + dq * 16 + i];
        float sp = fmaxf(v, 0.f) + log1pf(__expf(-fabsf(v)));
        dtile[dq * 16 + i][lsub] = sp;
    }
    __syncthreads();

    // overlay x tile on dead Wdt storage: xs[l][d]
    float (*xs)[65] = (float(*)[65])wlbuf;
    {
        #pragma unroll
        for (int i = 0; i < 4; ++i) {
            int f4i = tid + 256 * i;
            int l = f4i >> 4, m4 = (f4i & 15) << 2;
            float4 v = *(const float4*)(x + (size_t)(row0 + l) * 1024 + d0 + m4);
            xs[l][m4+0] = v.x; xs[l][m4+1] = v.y; xs[l][m4+2] = v.z; xs[l][m4+3] = v.w;
        }
    }
    __syncthreads();

    {
        int dp_ = tid >> 2, seg = tid & 3;
        int b = row0 >> 10, l0 = row0 & 1023;
        size_t off = ((size_t)b * 1024 + d0 + dp_) * 1024 + l0 + seg * 16;
        float* ddst = delta_t + off;
        float* udst = u_t + off;
        #pragma unroll
        for (int m = 0; m < 4; ++m) {
            int lb = seg * 16 + m * 4;
            float4 v;
            v.x = dtile[dp_][lb + 0];
            v.y = dtile[dp_][lb + 1];
            v.z = dtile[dp_][lb + 2];
            v.w = dtile[dp_][lb + 3];
            float4 u;
            u.x = v.x * xs[lb + 0][dp_];
            u.y = v.y * xs[lb + 1][dp_];
            u.z = v.z * xs[lb + 2][dp_];
            u.w = v.w * xs[lb + 3][dp_];
            ((float4*)ddst)[m] = v;
            ((float4*)udst)[m] = u;
        }
    }
}

// ============ Kernel 3: scan, n-SPLIT across wave pairs + fused transpose ====
__global__ __launch_bounds__(512, 4) void scan_kernel(
        const float* __restrict__ delta_t, const float* __restrict__ u_t,
        const float* __restrict__ Bg, const float* __restrict__ Cg,
        const float* __restrict__ A_log, const float* __restrict__ Dvec,
        float* __restrict__ yout) {
    const int bid0 = blockIdx.x;                       // 0..511
    const int bid  = (bid0 & 7) * 64 + (bid0 >> 3);    // XCD-chunked swizzle
    const int wv   = threadIdx.x >> 6;                 // wave 0..7
    const int ch   = wv >> 1;                          // chain-in-block 0..3
    const int half = wv & 1;                           // state half 0/1
    const int lane = threadIdx.x & 63;
    const int chain = bid * 4 + ch;                    // 0..2047
    const int b = chain >> 10;
    const int d = chain & 1023;
    const int l0 = lane * 16;

    __shared__ float ycomb[4][64][17];                 // padded: bank-conflict-free
    __shared__ float T[4][1088];                       // swizzled y tile

    const size_t choff = ((size_t)b * 1024 + d) * 1024 + l0;

    float dl[16], ul[16];
    #pragma unroll
    for (int k = 0; k < 4; ++k) {
        float4 v = *(const float4*)(delta_t + choff + k * 4);
        dl[4*k+0] = v.x; dl[4*k+1] = v.y; dl[4*k+2] = v.z; dl[4*k+3] = v.w;
    }
    #pragma unroll
    for (int k = 0; k < 4; ++k) {
        float4 v = *(const float4*)(u_t + choff + k * 4);
        ul[4*k+0] = v.x; ul[4*k+1] = v.y; ul[4*k+2] = v.z; ul[4*k+3] = v.w;
    }

    const float* Bp = Bg + (size_t)b * 16 * 1024 + l0;
    const float* Cp = Cg + (size_t)b * 16 * 1024 + l0;

    float y[16];
    if (half == 0) {
        const float Dd = Dvec[d];
        #pragma unroll
        for (int l = 0; l < 16; ++l)
            y[l] = ul[l] * __builtin_amdgcn_rcpf(dl[l]) * Dd;  // x*D via x=u/delta
    } else {
        #pragma unroll
        for (int l = 0; l < 16; ++l) y[l] = 0.f;
    }

    #pragma unroll 1
    for (int jn = 0; jn < 8; ++jn) {
        const int n = half * 8 + jn;
        const float a = -__expf(A_log[d * 16 + n]) * LOG2E;

        float local = 0.f;
        #pragma unroll
        for (int l = 0; l < 16; ++l)
            local += fmaxf(dl[l] * a, NEG7L2);
        float incl = wave_iscan(local);
        float c = incl - local;                  // exclusive prefix start

        float Bv[16], Cv[16];
        #pragma unroll
        for (int k = 0; k < 4; ++k) {
            float4 bv = *(const float4*)(Bp + (size_t)n * 1024 + k * 4);
            Bv[4*k+0] = bv.x; Bv[4*k+1] = bv.y; Bv[4*k+2] = bv.z; Bv[4*k+3] = bv.w;
            float4 cv = *(const float4*)(Cp + (size_t)n * 1024 + k * 4);
            Cv[4*k+0] = cv.x; Cv[4*k+1] = cv.y; Cv[4*k+2] = cv.z; Cv[4*k+3] = cv.w;
        }

        float g[16];
        float srun = 0.f;
        #pragma unroll
        for (int l = 0; l < 16; ++l) {
            c += fmaxf(dl[l] * a, NEG7L2);
            g[l] = Cv[l] * exp2f(c);             // c <= 0 always
            srun = fmaf(ul[l] * Bv[l], exp2f(fminf(-c, P20L2)), srun);
            y[l] = fmaf(g[l], srun, y[l]);
        }

        float incl2 = wave_iscan(srun);
        float lex = incl2 - srun;
        #pragma unroll
        for (int l = 0; l < 16; ++l)
            y[l] = fmaf(g[l], lex, y[l]);
    }

    // ---- combine halves (1 barrier), then fused transpose epilogue ----
    if (half == 1) {
        #pragma unroll
        for (int l = 0; l < 16; ++l)
            ycomb[ch][lane][l] = y[l];
    }
    __syncthreads();
    if (half == 0) {
        #pragma unroll
        for (int k = 0; k < 16; ++k) {
            int l = l0 + k;
            T[ch][l + (l >> 4)] = y[k] + ycomb[ch][lane][k];
        }
    }
    __syncthreads();

    {   // each thread emits 2 l-rows as float4 over d0..d0+3
        const int d0 = (bid * 4) & 1023;
        float* yb = yout + (size_t)b * 1024 * 1024 + d0;
        #pragma unroll
        for (int m = 0; m < 2; ++m) {
            int l = threadIdx.x * 2 + m;
            int sw = l + (l >> 4);
            float4 o = make_float4(T[0][sw], T[1][sw], T[2][sw], T[3][sw]);
            *(float4*)(yb + (size_t)l * 1024) = o;
        }
    }
}

extern "C" void kernel_launch(void* const* d_in, const int* in_sizes, int n_in,
                              void* d_out, int out_size, void* d_ws, size_t ws_size,
                              hipStream_t stream) {
    const float* x    = (const float*)d_in[0];
    const float* Wx   = (const float*)d_in[1];
    const float* Wdt  = (const float*)d_in[2];
    const float* bdt  = (const float*)d_in[3];
    const float* Alog = (const float*)d_in[4];
    const float* Dvec = (const float*)d_in[5];
    float* y = (float*)d_out;

    float* projdt  = (float*)d_ws;
    float* Bgp     = projdt + (size_t)2048 * 64;
    float* Cgp     = Bgp + (size_t)2 * 16 * 1024;
    float* delta_t = Cgp + (size_t)2 * 16 * 1024;
    float* u_t     = delta_t + (size_t)2 * 1024 * 1024;

    // DIAGNOSTIC ROUND: pipeline is idempotent (pure functions of inputs;
    // scan writes only yout). Replay x4 to measure marginal kernel cost:
    //   (T_4x - T_1x) / 3 = proj + delta + scan + 3*launch_overhead
    for (int it = 0; it < 4; ++it) {
        proj_kernel<<<256, 768, 0, stream>>>(x, Wx, projdt, Bgp, Cgp);
        delta_kernel<<<512, 256, 0, stream>>>(projdt, Wdt, bdt, x, delta_t, u_t);
        scan_kernel<<<512, 512, 0, stream>>>(delta_t, u_t, Bgp, Cgp, Alog, Dvec, y);
    }
}

// Round 19
// 215.732 us; speedup vs baseline: 1.2273x; 1.2273x over previous
//
#include <hip/hip_runtime.h>
#include <math.h>

#define D_INNER 1024
#define STATE   16
#define DT_RANK 64
#define NPROJ   96
#define LSEQ    1024
#define NBATCH  2
#define AMP     4    // DIAGNOSTIC: internal amplification, all kernels

#define LOG2E   1.4426950408889634f
#define NEG7L2  (-7.0f * LOG2E)     // clamp lo in log2 domain
#define P20L2   (20.0f * LOG2E)     // clamp hi in log2 domain

// ---- 64-lane inclusive scan via DPP (GCN idiom), 6 adds ----
template<int CTRL, int RMASK>
__device__ __forceinline__ float dppadd(float v) {
    int t = __builtin_amdgcn_update_dpp(0, __float_as_int(v), CTRL, RMASK, 0xf, false);
    return v + __int_as_float(t);
}
__device__ __forceinline__ float wave_iscan(float v) {
    v = dppadd<0x111, 0xf>(v);   // row_shr:1
    v = dppadd<0x112, 0xf>(v);   // row_shr:2
    v = dppadd<0x114, 0xf>(v);   // row_shr:4
    v = dppadd<0x118, 0xf>(v);   // row_shr:8
    v = dppadd<0x142, 0xa>(v);   // row_bcast:15 -> rows 1,3
    v = dppadd<0x143, 0xc>(v);   // row_bcast:31 -> rows 2,3
    return v;
}

// ============ Kernel 1: proj = x @ W_xproj ============
__global__ __launch_bounds__(768) void proj_kernel(
        const float* __restrict__ x, const float* __restrict__ Wx,
        float* __restrict__ projdt, float* __restrict__ Bg, float* __restrict__ Cg) {
    const int tid = threadIdx.x;
    const int j  = tid % 96;
    const int kq = tid / 96;              // 0..7
    const int row0 = blockIdx.x * 8;

    __shared__ float xs[8 * 1024];        // [r][k], 32 KB
    __shared__ float red[8][8][96];       // [kq][r][j], 24 KB

    for (int rep = 0; rep < AMP; ++rep) {
        __syncthreads();                  // rep-boundary safety
        {   // stage 8 rows of x (contiguous 32KB), coalesced float4
            const float4* src = (const float4*)(x + (size_t)row0 * 1024);
            #pragma unroll
            for (int i = 0; i < 3; ++i) {
                int idx = tid + 768 * i;  // 0..2047 float4s
                if (idx < 2048) {
                    float4 v = src[idx];
                    *(float4*)&xs[idx * 4] = v;
                }
            }
        }
        __syncthreads();

        const float* wp = Wx + (size_t)(kq * 128) * 96 + j;
        const float* xk = &xs[kq * 128];

        float a[8];
        #pragma unroll
        for (int r = 0; r < 8; ++r) a[r] = 0.f;

        #pragma unroll 8
        for (int k = 0; k < 128; ++k) {
            float w = wp[(size_t)k * 96];
            #pragma unroll
            for (int r = 0; r < 8; ++r)
                a[r] = fmaf(xk[r * 1024 + k], w, a[r]);
        }

        #pragma unroll
        for (int r = 0; r < 8; ++r) red[kq][r][j] = a[r];
        __syncthreads();

        {   // 768 outputs, one per thread
            const int r  = tid / 96;
            const int jj = tid % 96;
            float s = 0.f;
            #pragma unroll
            for (int p = 0; p < 8; ++p) s += red[p][r][jj];
            const int row = row0 + r;
            const int b = row >> 10, l = row & 1023;
            if (jj < 64)      projdt[(size_t)row * 64 + jj] = s;
            else if (jj < 80) Bg[((size_t)b * 16 + (jj - 64)) * 1024 + l] = s;
            else              Cg[((size_t)b * 16 + (jj - 80)) * 1024 + l] = s;
        }
    }
}

// ============ Kernel 2: delta (transposed) + u_t = delta * x (transposed) ====
__global__ __launch_bounds__(256) void delta_kernel(
        const float* __restrict__ projdt, const float* __restrict__ Wdt,
        const float* __restrict__ bdt, const float* __restrict__ x,
        float* __restrict__ delta_t, float* __restrict__ u_t) {
    const int bid = blockIdx.x;
    const int lt = bid >> 4;
    const int dt = bid & 15;
    const int row0 = lt * 64;
    const int d0 = dt * 64;
    const int tid = threadIdx.x;

    __shared__ float pl[64][69];
    __shared__ float wlbuf[64 * 68];      // Wdt tile; reused for x tile later
    __shared__ float dtile[64][65];
    float (*wl)[68] = (float(*)[68])wlbuf;

    for (int rep = 0; rep < AMP; ++rep) {
        __syncthreads();                  // rep-boundary: wlbuf overlay hazard
        {
            const float4* src = (const float4*)(projdt + (size_t)row0 * 64);
            #pragma unroll
            for (int i = 0; i < 4; ++i) {
                int f4i = tid + 256 * i;
                float4 v = src[f4i];
                int l = f4i >> 4, k4 = (f4i & 15) << 2;
                pl[l][k4+0] = v.x; pl[l][k4+1] = v.y; pl[l][k4+2] = v.z; pl[l][k4+3] = v.w;
            }
        }
        {
            #pragma unroll
            for (int i = 0; i < 4; ++i) {
                int f4i = tid + 256 * i;
                int k = f4i >> 4, m4 = (f4i & 15) << 2;
                float4 v = *(const float4*)(Wdt + (size_t)k * 1024 + d0 + m4);
                *(float4*)&wl[k][m4] = v;
            }
        }
        __syncthreads();

        const int lsub = tid & 63;
        const int dq = tid >> 6;
        float acc[16];
        #pragma unroll
        for (int i = 0; i < 16; ++i) acc[i] = 0.f;

        #pragma unroll 4
        for (int k = 0; k < 64; ++k) {
            float p = pl[lsub][k];
            const float4* wr = (const float4*)&wl[k][dq * 16];
            float4 w0 = wr[0], w1 = wr[1], w2 = wr[2], w3 = wr[3];
            acc[0]  = fmaf(p, w0.x, acc[0]);  acc[1]  = fmaf(p, w0.y, acc[1]);
            acc[2]  = fmaf(p, w0.z, acc[2]);  acc[3]  = fmaf(p, w0.w, acc[3]);
            acc[4]  = fmaf(p, w1.x, acc[4]);  acc[5]  = fmaf(p, w1.y, acc[5]);
            acc[6]  = fmaf(p, w1.z, acc[6]);  acc[7]  = fmaf(p, w1.w, acc[7]);
            acc[8]  = fmaf(p, w2.x, acc[8]);  acc[9]  = fmaf(p, w2.y, acc[9]);
            acc[10] = fmaf(p, w2.z, acc[10]); acc[11] = fmaf(p, w2.w, acc[11]);
            acc[12] = fmaf(p, w3.x, acc[12]); acc[13] = fmaf(p, w3.y, acc[13]);
            acc[14] = fmaf(p, w3.z, acc[14]); acc[15] = fmaf(p, w3.w, acc[15]);
        }

        #pragma unroll
        for (int i = 0; i < 16; ++i) {
            float v = acc[i] + bdt[d0 + dq * 16 + i];
            float sp = fmaxf(v, 0.f) + log1pf(__expf(-fabsf(v)));
            dtile[dq * 16 + i][lsub] = sp;
        }
        __syncthreads();

        // overlay x tile on dead Wdt storage: xs[l][d]
        float (*xs)[65] = (float(*)[65])wlbuf;
        {
            #pragma unroll
            for (int i = 0; i < 4; ++i) {
                int f4i = tid + 256 * i;
                int l = f4i >> 4, m4 = (f4i & 15) << 2;
                float4 v = *(const float4*)(x + (size_t)(row0 + l) * 1024 + d0 + m4);
                xs[l][m4+0] = v.x; xs[l][m4+1] = v.y; xs[l][m4+2] = v.z; xs[l][m4+3] = v.w;
            }
        }
        __syncthreads();

        {
            int dp_ = tid >> 2, seg = tid & 3;
            int b = row0 >> 10, l0 = row0 & 1023;
            size_t off = ((size_t)b * 1024 + d0 + dp_) * 1024 + l0 + seg * 16;
            float* ddst = delta_t + off;
            float* udst = u_t + off;
            #pragma unroll
            for (int m = 0; m < 4; ++m) {
                int lb = seg * 16 + m * 4;
                float4 v;
                v.x = dtile[dp_][lb + 0];
                v.y = dtile[dp_][lb + 1];
                v.z = dtile[dp_][lb + 2];
                v.w = dtile[dp_][lb + 3];
                float4 u;
                u.x = v.x * xs[lb + 0][dp_];
                u.y = v.y * xs[lb + 1][dp_];
                u.z = v.z * xs[lb + 2][dp_];
                u.w = v.w * xs[lb + 3][dp_];
                ((float4*)ddst)[m] = v;
                ((float4*)udst)[m] = u;
            }
        }
    }
}

// ============ Kernel 3: scan, n-SPLIT across wave pairs + fused transpose ====
__global__ __launch_bounds__(512, 4) void scan_kernel(
        const float* __restrict__ delta_t, const float* __restrict__ u_t,
        const float* __restrict__ Bg, const float* __restrict__ Cg,
        const float* __restrict__ A_log, const float* __restrict__ Dvec,
        float* __restrict__ yout) {
    const int bid0 = blockIdx.x;                       // 0..511
    const int bid  = (bid0 & 7) * 64 + (bid0 >> 3);    // XCD-chunked swizzle
    const int wv   = threadIdx.x >> 6;                 // wave 0..7
    const int ch   = wv >> 1;                          // chain-in-block 0..3
    const int half = wv & 1;                           // state half 0/1
    const int lane = threadIdx.x & 63;
    const int chain = bid * 4 + ch;                    // 0..2047
    const int b = chain >> 10;
    const int d = chain & 1023;
    const int l0 = lane * 16;

    __shared__ float ycomb[4][64][17];                 // padded: bank-conflict-free
    __shared__ float T[4][1088];                       // swizzled y tile

    const size_t choff = ((size_t)b * 1024 + d) * 1024 + l0;

    for (int rep = 0; rep < AMP; ++rep) {
        __syncthreads();                  // rep-boundary safety

        float dl[16], ul[16];
        #pragma unroll
        for (int k = 0; k < 4; ++k) {
            float4 v = *(const float4*)(delta_t + choff + k * 4);
            dl[4*k+0] = v.x; dl[4*k+1] = v.y; dl[4*k+2] = v.z; dl[4*k+3] = v.w;
        }
        #pragma unroll
        for (int k = 0; k < 4; ++k) {
            float4 v = *(const float4*)(u_t + choff + k * 4);
            ul[4*k+0] = v.x; ul[4*k+1] = v.y; ul[4*k+2] = v.z; ul[4*k+3] = v.w;
        }

        const float* Bp = Bg + (size_t)b * 16 * 1024 + l0;
        const float* Cp = Cg + (size_t)b * 16 * 1024 + l0;

        float y[16];
        if (half == 0) {
            const float Dd = Dvec[d];
            #pragma unroll
            for (int l = 0; l < 16; ++l)
                y[l] = ul[l] * __builtin_amdgcn_rcpf(dl[l]) * Dd;  // x*D via x=u/delta
        } else {
            #pragma unroll
            for (int l = 0; l < 16; ++l) y[l] = 0.f;
        }

        #pragma unroll 1
        for (int jn = 0; jn < 8; ++jn) {
            const int n = half * 8 + jn;
            const float a = -__expf(A_log[d * 16 + n]) * LOG2E;

            float local = 0.f;
            #pragma unroll
            for (int l = 0; l < 16; ++l)
                local += fmaxf(dl[l] * a, NEG7L2);
            float incl = wave_iscan(local);
            float c = incl - local;                  // exclusive prefix start

            float Bv[16], Cv[16];
            #pragma unroll
            for (int k = 0; k < 4; ++k) {
                float4 bv = *(const float4*)(Bp + (size_t)n * 1024 + k * 4);
                Bv[4*k+0] = bv.x; Bv[4*k+1] = bv.y; Bv[4*k+2] = bv.z; Bv[4*k+3] = bv.w;
                float4 cv = *(const float4*)(Cp + (size_t)n * 1024 + k * 4);
                Cv[4*k+0] = cv.x; Cv[4*k+1] = cv.y; Cv[4*k+2] = cv.z; Cv[4*k+3] = cv.w;
            }

            float g[16];
            float srun = 0.f;
            #pragma unroll
            for (int l = 0; l < 16; ++l) {
                c += fmaxf(dl[l] * a, NEG7L2);
                g[l] = Cv[l] * exp2f(c);             // c <= 0 always
                srun = fmaf(ul[l] * Bv[l], exp2f(fminf(-c, P20L2)), srun);
                y[l] = fmaf(g[l], srun, y[l]);
            }

            float incl2 = wave_iscan(srun);
            float lex = incl2 - srun;
            #pragma unroll
            for (int l = 0; l < 16; ++l)
                y[l] = fmaf(g[l], lex, y[l]);
        }

        // ---- combine halves (1 barrier), then fused transpose epilogue ----
        if (half == 1) {
            #pragma unroll
            for (int l = 0; l < 16; ++l)
                ycomb[ch][lane][l] = y[l];
        }
        __syncthreads();
        if (half == 0) {
            #pragma unroll
            for (int k = 0; k < 16; ++k) {
                int l = l0 + k;
                T[ch][l + (l >> 4)] = y[k] + ycomb[ch][lane][k];
            }
        }
        __syncthreads();

        {   // each thread emits 2 l-rows as float4 over d0..d0+3
            const int d0 = (bid * 4) & 1023;
            float* yb = yout + (size_t)b * 1024 * 1024 + d0;
            #pragma unroll
            for (int m = 0; m < 2; ++m) {
                int l = threadIdx.x * 2 + m;
                int sw = l + (l >> 4);
                float4 o = make_float4(T[0][sw], T[1][sw], T[2][sw], T[3][sw]);
                *(float4*)(yb + (size_t)l * 1024) = o;
            }
        }
    }
}

extern "C" void kernel_launch(void* const* d_in, const int* in_sizes, int n_in,
                              void* d_out, int out_size, void* d_ws, size_t ws_size,
                              hipStream_t stream) {
    const float* x    = (const float*)d_in[0];
    const float* Wx   = (const float*)d_in[1];
    const float* Wdt  = (const float*)d_in[2];
    const float* bdt  = (const float*)d_in[3];
    const float* Alog = (const float*)d_in[4];
    const float* Dvec = (const float*)d_in[5];
    float* y = (float*)d_out;

    float* projdt  = (float*)d_ws;
    float* Bgp     = projdt + (size_t)2048 * 64;
    float* Cgp     = Bgp + (size_t)2 * 16 * 1024;
    float* delta_t = Cgp + (size_t)2 * 16 * 1024;
    float* u_t     = delta_t + (size_t)2 * 1024 * 1024;

    // DIAGNOSTIC ROUND 2: each kernel internally amplified x4 so each
    // dispatch duration = 4x its true cost -> all three enter rocprof top-5
    // with full counters. (T - 70.3)/3 = P + D + S.
    proj_kernel<<<256, 768, 0, stream>>>(x, Wx, projdt, Bgp, Cgp);
    delta_kernel<<<512, 256, 0, stream>>>(projdt, Wdt, bdt, x, delta_t, u_t);
    scan_kernel<<<512, 512, 0, stream>>>(delta_t, u_t, Bgp, Cgp, Alog, Dvec, y);
}

// Round 20
// 73.858 us; speedup vs baseline: 3.5849x; 2.9209x over previous
//
#include <hip/hip_runtime.h>
#include <math.h>

#define D_INNER 1024
#define STATE   16
#define DT_RANK 64
#define NPROJ   96
#define LSEQ    1024
#define NBATCH  2

#define LOG2E   1.4426950408889634f
#define NEG7L2  (-7.0f * LOG2E)     // clamp lo in log2 domain
#define P20L2   (20.0f * LOG2E)     // clamp hi in log2 domain

// ---- 64-lane inclusive scan via DPP (GCN idiom), 6 adds ----
template<int CTRL, int RMASK>
__device__ __forceinline__ float dppadd(float v) {
    int t = __builtin_amdgcn_update_dpp(0, __float_as_int(v), CTRL, RMASK, 0xf, false);
    return v + __int_as_float(t);
}
__device__ __forceinline__ float wave_iscan(float v) {
    v = dppadd<0x111, 0xf>(v);   // row_shr:1
    v = dppadd<0x112, 0xf>(v);   // row_shr:2
    v = dppadd<0x114, 0xf>(v);   // row_shr:4
    v = dppadd<0x118, 0xf>(v);   // row_shr:8
    v = dppadd<0x142, 0xa>(v);   // row_bcast:15 -> rows 1,3
    v = dppadd<0x143, 0xc>(v);   // row_bcast:31 -> rows 2,3
    return v;
}

// ============ Kernel 1: proj = x @ W_xproj ============
// 256 blocks x 768 threads; 8 rows/block, K split 8x128; x staged in LDS.
// xs read as float4 per 4-k group: 8 b128 LDS instrs per group (was 32 b32).
__global__ __launch_bounds__(768) void proj_kernel(
        const float* __restrict__ x, const float* __restrict__ Wx,
        float* __restrict__ projdt, float* __restrict__ Bg, float* __restrict__ Cg) {
    const int tid = threadIdx.x;
    const int j  = tid % 96;
    const int kq = tid / 96;              // 0..7
    const int row0 = blockIdx.x * 8;

    __shared__ float xs[8 * 1024];        // [r][k], 32 KB
    __shared__ float red[8][8][96];       // [kq][r][j], 24 KB

    {   // stage 8 rows of x (contiguous 32KB), coalesced float4
        const float4* src = (const float4*)(x + (size_t)row0 * 1024);
        #pragma unroll
        for (int i = 0; i < 3; ++i) {
            int idx = tid + 768 * i;      // 0..2047 float4s
            if (idx < 2048) {
                float4 v = src[idx];
                *(float4*)&xs[idx * 4] = v;
            }
        }
    }
    __syncthreads();

    const float* wp = Wx + (size_t)(kq * 128) * 96 + j;
    const float* xk = &xs[kq * 128];

    float a[8];
    #pragma unroll
    for (int r = 0; r < 8; ++r) a[r] = 0.f;

    #pragma unroll 2
    for (int k4 = 0; k4 < 128; k4 += 4) {
        float w0 = wp[(size_t)(k4 + 0) * 96];
        float w1 = wp[(size_t)(k4 + 1) * 96];
        float w2 = wp[(size_t)(k4 + 2) * 96];
        float w3 = wp[(size_t)(k4 + 3) * 96];
        #pragma unroll
        for (int r = 0; r < 8; ++r) {
            float4 xv = *(const float4*)&xk[r * 1024 + k4];   // 1 b128, 4 k's
            float t = a[r];
            t = fmaf(xv.x, w0, t);
            t = fmaf(xv.y, w1, t);
            t = fmaf(xv.z, w2, t);
            t = fmaf(xv.w, w3, t);
            a[r] = t;
        }
    }

    #pragma unroll
    for (int r = 0; r < 8; ++r) red[kq][r][j] = a[r];
    __syncthreads();

    {   // 768 outputs, one per thread
        const int r  = tid / 96;
        const int jj = tid % 96;
        float s = 0.f;
        #pragma unroll
        for (int p = 0; p < 8; ++p) s += red[p][r][jj];
        const int row = row0 + r;
        const int b = row >> 10, l = row & 1023;
        if (jj < 64)      projdt[(size_t)row * 64 + jj] = s;
        else if (jj < 80) Bg[((size_t)b * 16 + (jj - 64)) * 1024 + l] = s;
        else              Cg[((size_t)b * 16 + (jj - 80)) * 1024 + l] = s;
    }
}

// ============ Kernel 2: delta (transposed) + u_t = delta * x (transposed) ====
// Wdt NOT staged in LDS: read via readfirstlane-scalarized base -> s_load
// (constant-cache path, no LDS/VALU slot). Wdt is 256KB, L2-resident.
__global__ __launch_bounds__(256) void delta_kernel(
        const float* __restrict__ projdt, const float* __restrict__ Wdt,
        const float* __restrict__ bdt, const float* __restrict__ x,
        float* __restrict__ delta_t, float* __restrict__ u_t) {
    const int bid = blockIdx.x;
    const int lt = bid >> 4;
    const int dt = bid & 15;
    const int row0 = lt * 64;
    const int d0 = dt * 64;
    const int tid = threadIdx.x;

    __shared__ float pl[64][69];
    __shared__ float dtile[64][65];
    __shared__ float xsb[64][65];

    {   // stage projdt tile
        const float4* src = (const float4*)(projdt + (size_t)row0 * 64);
        #pragma unroll
        for (int i = 0; i < 4; ++i) {
            int f4i = tid + 256 * i;
            float4 v = src[f4i];
            int l = f4i >> 4, k4 = (f4i & 15) << 2;
            pl[l][k4+0] = v.x; pl[l][k4+1] = v.y; pl[l][k4+2] = v.z; pl[l][k4+3] = v.w;
        }
    }
    {   // stage x tile
        #pragma unroll
        for (int i = 0; i < 4; ++i) {
            int f4i = tid + 256 * i;
            int l = f4i >> 4, m4 = (f4i & 15) << 2;
            float4 v = *(const float4*)(x + (size_t)(row0 + l) * 1024 + d0 + m4);
            xsb[l][m4+0] = v.x; xsb[l][m4+1] = v.y; xsb[l][m4+2] = v.z; xsb[l][m4+3] = v.w;
        }
    }
    __syncthreads();

    const int lsub = tid & 63;
    const int dq = tid >> 6;
    // scalarized weight base: wave-uniform -> SGPR -> s_load path
    const int dbase = __builtin_amdgcn_readfirstlane(d0 + dq * 16);
    const float* wb = Wdt + dbase;

    float acc[16];
    #pragma unroll
    for (int i = 0; i < 16; ++i) acc[i] = 0.f;

    #pragma unroll 2
    for (int k = 0; k < 64; ++k) {
        float p = pl[lsub][k];
        const float* wr = wb + (size_t)k * 1024;
        #pragma unroll
        for (int i = 0; i < 16; ++i)
            acc[i] = fmaf(p, wr[i], acc[i]);    // wr[i]: scalar load (SGPR src)
    }

    #pragma unroll
    for (int i = 0; i < 16; ++i) {
        float v = acc[i] + bdt[d0 + dq * 16 + i];
        float sp = fmaxf(v, 0.f) + log1pf(__expf(-fabsf(v)));
        dtile[dq * 16 + i][lsub] = sp;
    }
    __syncthreads();

    {
        int dp_ = tid >> 2, seg = tid & 3;
        int b = row0 >> 10, l0 = row0 & 1023;
        size_t off = ((size_t)b * 1024 + d0 + dp_) * 1024 + l0 + seg * 16;
        float* ddst = delta_t + off;
        float* udst = u_t + off;
        #pragma unroll
        for (int m = 0; m < 4; ++m) {
            int lb = seg * 16 + m * 4;
            float4 v;
            v.x = dtile[dp_][lb + 0];
            v.y = dtile[dp_][lb + 1];
            v.z = dtile[dp_][lb + 2];
            v.w = dtile[dp_][lb + 3];
            float4 u;
            u.x = v.x * xsb[lb + 0][dp_];
            u.y = v.y * xsb[lb + 1][dp_];
            u.z = v.z * xsb[lb + 2][dp_];
            u.w = v.w * xsb[lb + 3][dp_];
            ((float4*)ddst)[m] = v;
            ((float4*)udst)[m] = u;
        }
    }
}

// ============ Kernel 3: scan, n-SPLIT across wave pairs + fused transpose ====
// pp[16] cached from pass 1 (chain reuses clamped values; -14% issue).
__global__ __launch_bounds__(512, 4) void scan_kernel(
        const float* __restrict__ delta_t, const float* __restrict__ u_t,
        const float* __restrict__ Bg, const float* __restrict__ Cg,
        const float* __restrict__ A_log, const float* __restrict__ Dvec,
        float* __restrict__ yout) {
    const int bid0 = blockIdx.x;                       // 0..511
    const int bid  = (bid0 & 7) * 64 + (bid0 >> 3);    // XCD-chunked swizzle
    const int wv   = threadIdx.x >> 6;                 // wave 0..7
    const int ch   = wv >> 1;                          // chain-in-block 0..3
    const int half = wv & 1;                           // state half 0/1
    const int lane = threadIdx.x & 63;
    const int chain = bid * 4 + ch;                    // 0..2047
    const int b = chain >> 10;
    const int d = chain & 1023;
    const int l0 = lane * 16;

    __shared__ float ycomb[4][64][17];                 // padded: bank-conflict-free
    __shared__ float T[4][1088];                       // swizzled y tile

    const size_t choff = ((size_t)b * 1024 + d) * 1024 + l0;

    float dl[16], ul[16];
    #pragma unroll
    for (int k = 0; k < 4; ++k) {
        float4 v = *(const float4*)(delta_t + choff + k * 4);
        dl[4*k+0] = v.x; dl[4*k+1] = v.y; dl[4*k+2] = v.z; dl[4*k+3] = v.w;
    }
    #pragma unroll
    for (int k = 0; k < 4; ++k) {
        float4 v = *(const float4*)(u_t + choff + k * 4);
        ul[4*k+0] = v.x; ul[4*k+1] = v.y; ul[4*k+2] = v.z; ul[4*k+3] = v.w;
    }

    const float* Bp = Bg + (size_t)b * 16 * 1024 + l0;
    const float* Cp = Cg + (size_t)b * 16 * 1024 + l0;

    float y[16];
    if (half == 0) {
        const float Dd = Dvec[d];
        #pragma unroll
        for (int l = 0; l < 16; ++l)
            y[l] = ul[l] * __builtin_amdgcn_rcpf(dl[l]) * Dd;  // x*D via x=u/delta
    } else {
        #pragma unroll
        for (int l = 0; l < 16; ++l) y[l] = 0.f;
    }

    #pragma unroll 1
    for (int jn = 0; jn < 8; ++jn) {
        const int n = half * 8 + jn;
        const float a = -__expf(A_log[d * 16 + n]) * LOG2E;

        // pass 1: clamped p values cached; lane sum; in-wave exclusive scan
        float pp[16];
        float local = 0.f;
        #pragma unroll
        for (int l = 0; l < 16; ++l) {
            pp[l] = fmaxf(dl[l] * a, NEG7L2);
            local += pp[l];
        }
        float incl = wave_iscan(local);
        float c = incl - local;                  // exclusive prefix start

        float Bv[16], Cv[16];
        #pragma unroll
        for (int k = 0; k < 4; ++k) {
            float4 bv = *(const float4*)(Bp + (size_t)n * 1024 + k * 4);
            Bv[4*k+0] = bv.x; Bv[4*k+1] = bv.y; Bv[4*k+2] = bv.z; Bv[4*k+3] = bv.w;
            float4 cv = *(const float4*)(Cp + (size_t)n * 1024 + k * 4);
            Cv[4*k+0] = cv.x; Cv[4*k+1] = cv.y; Cv[4*k+2] = cv.z; Cv[4*k+3] = cv.w;
        }

        // serial chain over 16 l (reuses pp): g cached, y inline
        float g[16];
        float srun = 0.f;
        #pragma unroll
        for (int l = 0; l < 16; ++l) {
            c += pp[l];
            g[l] = Cv[l] * exp2f(c);             // c <= 0 always
            srun = fmaf(ul[l] * Bv[l], exp2f(fminf(-c, P20L2)), srun);
            y[l] = fmaf(g[l], srun, y[l]);
        }

        float incl2 = wave_iscan(srun);
        float lex = incl2 - srun;
        #pragma unroll
        for (int l = 0; l < 16; ++l)
            y[l] = fmaf(g[l], lex, y[l]);
    }

    // ---- combine halves (1 barrier), then fused transpose epilogue ----
    if (half == 1) {
        #pragma unroll
        for (int l = 0; l < 16; ++l)
            ycomb[ch][lane][l] = y[l];
    }
    __syncthreads();
    if (half == 0) {
        #pragma unroll
        for (int k = 0; k < 16; ++k) {
            int l = l0 + k;
            T[ch][l + (l >> 4)] = y[k] + ycomb[ch][lane][k];
        }
    }
    __syncthreads();

    {   // each thread emits 2 l-rows as float4 over d0..d0+3
        const int d0 = (bid * 4) & 1023;
        float* yb = yout + (size_t)b * 1024 * 1024 + d0;
        #pragma unroll
        for (int m = 0; m < 2; ++m) {
            int l = threadIdx.x * 2 + m;
            int sw = l + (l >> 4);
            float4 o = make_float4(T[0][sw], T[1][sw], T[2][sw], T[3][sw]);
            *(float4*)(yb + (size_t)l * 1024) = o;
        }
    }
}

extern "C" void kernel_launch(void* const* d_in, const int* in_sizes, int n_in,
                              void* d_out, int out_size, void* d_ws, size_t ws_size,
                              hipStream_t stream) {
    const float* x    = (const float*)d_in[0];
    const float* Wx   = (const float*)d_in[1];
    const float* Wdt  = (const float*)d_in[2];
    const float* bdt  = (const float*)d_in[3];
    const float* Alog = (const float*)d_in[4];
    const float* Dvec = (const float*)d_in[5];
    float* y = (float*)d_out;

    float* projdt  = (float*)d_ws;
    float* Bgp     = projdt + (size_t)2048 * 64;
    float* Cgp     = Bgp + (size_t)2 * 16 * 1024;
    float* delta_t = Cgp + (size_t)2 * 16 * 1024;
    float* u_t     = delta_t + (size_t)2 * 1024 * 1024;

    proj_kernel<<<256, 768, 0, stream>>>(x, Wx, projdt, Bgp, Cgp);
    delta_kernel<<<512, 256, 0, stream>>>(projdt, Wdt, bdt, x, delta_t, u_t);
    scan_kernel<<<512, 512, 0, stream>>>(delta_t, u_t, Bgp, Cgp, Alog, Dvec, y);
}

// Round 21
// 66.116 us; speedup vs baseline: 4.0047x; 1.1171x over previous
//
#include <hip/hip_runtime.h>
#include <math.h>

#define D_INNER 1024
#define STATE   16
#define DT_RANK 64
#define NPROJ   96
#define LSEQ    1024
#define NBATCH  2

#define LOG2E   1.4426950408889634f
#define NEG7L2  (-7.0f * LOG2E)     // clamp lo in log2 domain
#define P20L2   (20.0f * LOG2E)     // clamp hi in log2 domain

// ---- 64-lane inclusive scan via DPP (GCN idiom), 6 adds ----
template<int CTRL, int RMASK>
__device__ __forceinline__ float dppadd(float v) {
    int t = __builtin_amdgcn_update_dpp(0, __float_as_int(v), CTRL, RMASK, 0xf, false);
    return v + __int_as_float(t);
}
__device__ __forceinline__ float wave_iscan(float v) {
    v = dppadd<0x111, 0xf>(v);   // row_shr:1
    v = dppadd<0x112, 0xf>(v);   // row_shr:2
    v = dppadd<0x114, 0xf>(v);   // row_shr:4
    v = dppadd<0x118, 0xf>(v);   // row_shr:8
    v = dppadd<0x142, 0xa>(v);   // row_bcast:15 -> rows 1,3
    v = dppadd<0x143, 0xc>(v);   // row_bcast:31 -> rows 2,3
    return v;
}

// ============ Kernel 1 (FUSED): proj + delta + u, one kernel ============
// 256 blocks x 768 threads; 8 rows/block.
// Phase A (r17 proj): stage x in LDS; compute proj; Bg/Cg to global;
//   dt_inter kept in LDS pdl[8][64] (no projdt round-trip).
// Phase B: thread t owns column d (2 passes: d=t, d=t+768): delta = softplus
//   (dot(pdl[r], Wdt[:,d]) + bdt[d]); u = delta * xs[r][d]; write 8
//   contiguous-l floats per (d) into delta_t/u_t [b][d][l].
__global__ __launch_bounds__(768) void projdelta_kernel(
        const float* __restrict__ x, const float* __restrict__ Wx,
        const float* __restrict__ Wdt, const float* __restrict__ bdt,
        float* __restrict__ Bg, float* __restrict__ Cg,
        float* __restrict__ delta_t, float* __restrict__ u_t) {
    const int tid = threadIdx.x;
    const int j  = tid % 96;
    const int kq = tid / 96;              // 0..7
    const int row0 = blockIdx.x * 8;

    __shared__ float xs[8 * 1024];        // [r][k], 32 KB
    __shared__ float red[8][8][96];       // [kq][r][j], 24 KB
    __shared__ float pdl[8][64];          // dt_inter rows, 2 KB

    {   // stage 8 rows of x (contiguous 32KB), coalesced float4
        const float4* src = (const float4*)(x + (size_t)row0 * 1024);
        #pragma unroll
        for (int i = 0; i < 3; ++i) {
            int idx = tid + 768 * i;      // 0..2047 float4s
            if (idx < 2048) {
                float4 v = src[idx];
                *(float4*)&xs[idx * 4] = v;
            }
        }
    }
    __syncthreads();

    // ---- Phase A: proj ----
    {
        const float* wp = Wx + (size_t)(kq * 128) * 96 + j;
        const float* xk = &xs[kq * 128];

        float a[8];
        #pragma unroll
        for (int r = 0; r < 8; ++r) a[r] = 0.f;

        #pragma unroll 8
        for (int k = 0; k < 128; ++k) {
            float w = wp[(size_t)k * 96];
            #pragma unroll
            for (int r = 0; r < 8; ++r)
                a[r] = fmaf(xk[r * 1024 + k], w, a[r]);
        }

        #pragma unroll
        for (int r = 0; r < 8; ++r) red[kq][r][j] = a[r];
    }
    __syncthreads();

    {   // 768 outputs, one per thread
        const int r  = tid / 96;
        const int jj = tid % 96;
        float s = 0.f;
        #pragma unroll
        for (int p = 0; p < 8; ++p) s += red[p][r][jj];
        const int row = row0 + r;
        const int b = row >> 10, l = row & 1023;
        if (jj < 64)      pdl[r][jj] = s;
        else if (jj < 80) Bg[((size_t)b * 16 + (jj - 64)) * 1024 + l] = s;
        else              Cg[((size_t)b * 16 + (jj - 80)) * 1024 + l] = s;
    }
    __syncthreads();

    // ---- Phase B: delta + u for these 8 rows, all 1024 d ----
    const int b  = row0 >> 10;
    const int l0 = row0 & 1023;
    #pragma unroll 1
    for (int it = 0; it < 2; ++it) {
        const int d = tid + it * 768;
        if (d < 1024) {
            const float bb = bdt[d];
            float acc[8];
            #pragma unroll
            for (int r = 0; r < 8; ++r) acc[r] = bb;

            #pragma unroll 1
            for (int c = 0; c < 4; ++c) {       // k chunks of 16
                float w[16];
                #pragma unroll
                for (int kk = 0; kk < 16; ++kk)
                    w[kk] = Wdt[(size_t)(c * 16 + kk) * 1024 + d];  // coalesced
                #pragma unroll
                for (int r = 0; r < 8; ++r) {
                    const float4 p0 = *(const float4*)&pdl[r][c * 16 + 0];
                    const float4 p1 = *(const float4*)&pdl[r][c * 16 + 4];
                    const float4 p2 = *(const float4*)&pdl[r][c * 16 + 8];
                    const float4 p3 = *(const float4*)&pdl[r][c * 16 + 12];
                    float t = acc[r];
                    t = fmaf(p0.x, w[0],  t); t = fmaf(p0.y, w[1],  t);
                    t = fmaf(p0.z, w[2],  t); t = fmaf(p0.w, w[3],  t);
                    t = fmaf(p1.x, w[4],  t); t = fmaf(p1.y, w[5],  t);
                    t = fmaf(p1.z, w[6],  t); t = fmaf(p1.w, w[7],  t);
                    t = fmaf(p2.x, w[8],  t); t = fmaf(p2.y, w[9],  t);
                    t = fmaf(p2.z, w[10], t); t = fmaf(p2.w, w[11], t);
                    t = fmaf(p3.x, w[12], t); t = fmaf(p3.y, w[13], t);
                    t = fmaf(p3.z, w[14], t); t = fmaf(p3.w, w[15], t);
                    acc[r] = t;
                }
            }

            float od[8], ou[8];
            #pragma unroll
            for (int r = 0; r < 8; ++r) {
                float v = acc[r];
                float sp = fmaxf(v, 0.f) + log1pf(__expf(-fabsf(v)));
                od[r] = sp;
                ou[r] = sp * xs[r * 1024 + d];
            }
            const size_t off = ((size_t)b * 1024 + d) * 1024 + l0;
            *(float4*)(delta_t + off)     = make_float4(od[0], od[1], od[2], od[3]);
            *(float4*)(delta_t + off + 4) = make_float4(od[4], od[5], od[6], od[7]);
            *(float4*)(u_t + off)     = make_float4(ou[0], ou[1], ou[2], ou[3]);
            *(float4*)(u_t + off + 4) = make_float4(ou[4], ou[5], ou[6], ou[7]);
        }
    }
}

// ============ Kernel 2: scan, n-SPLIT across wave pairs + fused transpose ====
// (r17 verbatim — best-known scan)
__global__ __launch_bounds__(512, 4) void scan_kernel(
        const float* __restrict__ delta_t, const float* __restrict__ u_t,
        const float* __restrict__ Bg, const float* __restrict__ Cg,
        const float* __restrict__ A_log, const float* __restrict__ Dvec,
        float* __restrict__ yout) {
    const int bid0 = blockIdx.x;                       // 0..511
    const int bid  = (bid0 & 7) * 64 + (bid0 >> 3);    // XCD-chunked swizzle
    const int wv   = threadIdx.x >> 6;                 // wave 0..7
    const int ch   = wv >> 1;                          // chain-in-block 0..3
    const int half = wv & 1;                           // state half 0/1
    const int lane = threadIdx.x & 63;
    const int chain = bid * 4 + ch;                    // 0..2047
    const int b = chain >> 10;
    const int d = chain & 1023;
    const int l0 = lane * 16;

    __shared__ float ycomb[4][64][17];                 // padded: bank-conflict-free
    __shared__ float T[4][1088];                       // swizzled y tile

    const size_t choff = ((size_t)b * 1024 + d) * 1024 + l0;

    float dl[16], ul[16];
    #pragma unroll
    for (int k = 0; k < 4; ++k) {
        float4 v = *(const float4*)(delta_t + choff + k * 4);
        dl[4*k+0] = v.x; dl[4*k+1] = v.y; dl[4*k+2] = v.z; dl[4*k+3] = v.w;
    }
    #pragma unroll
    for (int k = 0; k < 4; ++k) {
        float4 v = *(const float4*)(u_t + choff + k * 4);
        ul[4*k+0] = v.x; ul[4*k+1] = v.y; ul[4*k+2] = v.z; ul[4*k+3] = v.w;
    }

    const float* Bp = Bg + (size_t)b * 16 * 1024 + l0;
    const float* Cp = Cg + (size_t)b * 16 * 1024 + l0;

    float y[16];
    if (half == 0) {
        const float Dd = Dvec[d];
        #pragma unroll
        for (int l = 0; l < 16; ++l)
            y[l] = ul[l] * __builtin_amdgcn_rcpf(dl[l]) * Dd;  // x*D via x=u/delta
    } else {
        #pragma unroll
        for (int l = 0; l < 16; ++l) y[l] = 0.f;
    }

    #pragma unroll 1
    for (int jn = 0; jn < 8; ++jn) {
        const int n = half * 8 + jn;
        const float a = -__expf(A_log[d * 16 + n]) * LOG2E;

        float local = 0.f;
        #pragma unroll
        for (int l = 0; l < 16; ++l)
            local += fmaxf(dl[l] * a, NEG7L2);
        float incl = wave_iscan(local);
        float c = incl - local;                  // exclusive prefix start

        float Bv[16], Cv[16];
        #pragma unroll
        for (int k = 0; k < 4; ++k) {
            float4 bv = *(const float4*)(Bp + (size_t)n * 1024 + k * 4);
            Bv[4*k+0] = bv.x; Bv[4*k+1] = bv.y; Bv[4*k+2] = bv.z; Bv[4*k+3] = bv.w;
            float4 cv = *(const float4*)(Cp + (size_t)n * 1024 + k * 4);
            Cv[4*k+0] = cv.x; Cv[4*k+1] = cv.y; Cv[4*k+2] = cv.z; Cv[4*k+3] = cv.w;
        }

        float g[16];
        float srun = 0.f;
        #pragma unroll
        for (int l = 0; l < 16; ++l) {
            c += fmaxf(dl[l] * a, NEG7L2);
            g[l] = Cv[l] * exp2f(c);             // c <= 0 always
            srun = fmaf(ul[l] * Bv[l], exp2f(fminf(-c, P20L2)), srun);
            y[l] = fmaf(g[l], srun, y[l]);
        }

        float incl2 = wave_iscan(srun);
        float lex = incl2 - srun;
        #pragma unroll
        for (int l = 0; l < 16; ++l)
            y[l] = fmaf(g[l], lex, y[l]);
    }

    // ---- combine halves (1 barrier), then fused transpose epilogue ----
    if (half == 1) {
        #pragma unroll
        for (int l = 0; l < 16; ++l)
            ycomb[ch][lane][l] = y[l];
    }
    __syncthreads();
    if (half == 0) {
        #pragma unroll
        for (int k = 0; k < 16; ++k) {
            int l = l0 + k;
            T[ch][l + (l >> 4)] = y[k] + ycomb[ch][lane][k];
        }
    }
    __syncthreads();

    {   // each thread emits 2 l-rows as float4 over d0..d0+3
        const int d0 = (bid * 4) & 1023;
        float* yb = yout + (size_t)b * 1024 * 1024 + d0;
        #pragma unroll
        for (int m = 0; m < 2; ++m) {
            int l = threadIdx.x * 2 + m;
            int sw = l + (l >> 4);
            float4 o = make_float4(T[0][sw], T[1][sw], T[2][sw], T[3][sw]);
            *(float4*)(yb + (size_t)l * 1024) = o;
        }
    }
}

extern "C" void kernel_launch(void* const* d_in, const int* in_sizes, int n_in,
                              void* d_out, int out_size, void* d_ws, size_t ws_size,
                              hipStream_t stream) {
    const float* x    = (const float*)d_in[0];
    const float* Wx   = (const float*)d_in[1];
    const float* Wdt  = (const float*)d_in[2];
    const float* bdt  = (const float*)d_in[3];
    const float* Alog = (const float*)d_in[4];
    const float* Dvec = (const float*)d_in[5];
    float* y = (float*)d_out;

    // ws (floats): Bg 32768 | Cg 32768 | delta_t 2M | u_t 2M  (~16.5 MB)
    float* Bgp     = (float*)d_ws;
    float* Cgp     = Bgp + (size_t)2 * 16 * 1024;
    float* delta_t = Cgp + (size_t)2 * 16 * 1024;
    float* u_t     = delta_t + (size_t)2 * 1024 * 1024;

    projdelta_kernel<<<256, 768, 0, stream>>>(x, Wx, Wdt, bdt, Bgp, Cgp, delta_t, u_t);
    scan_kernel<<<512, 512, 0, stream>>>(delta_t, u_t, Bgp, Cgp, Alog, Dvec, y);
}